// Round 2
// baseline (224.211 us; speedup 1.0000x reference)
//
#include <hip/hip_runtime.h>

// EquiConv fused MFMA kernel for MI355X (gfx950) — round 2: K-split 4.
// Block = 16 edges, 4 waves; wave w owns u-quarter of each einsum (A-gen VALU
// splits with K). 1250 blocks -> 5000 waves (4.9/SIMD demand), LDS 40.7KB ->
// 4 blocks/CU. Cross-wave tile reduction via 12-slot LDS buffer. FC chain
// N-split across waves. Fragment layouts per learn_hip m89/m120 (verified R1).

#define E_TOT 20000

typedef __attribute__((ext_vector_type(8))) short short8;
typedef __attribute__((ext_vector_type(4))) float f32x4;
typedef __attribute__((ext_vector_type(2))) __bf16 bf16x2;

// ws layout offsets (ushort units); packed idx = ((chunk*NT + t)*64 + lane)*8 + j
#define OFF_SS 0        // K=4096 NT=6
#define OFF_VV 393216   // K=1024 NT=6
#define OFF_SV 491520   // K=2048 NT=2
#define OFF_VS 557056   // K=2048 NT=2
#define OFF_F1 622592   // K=128  NT=4
#define OFF_F2 630784   // K=64   NT=4
#define OFF_F3 634880   // K=64   NT=6
#define N_TOTAL 641024

__device__ __forceinline__ unsigned short f2b(float f){
  return __builtin_bit_cast(unsigned short, (__bf16)f);
}
__device__ __forceinline__ unsigned f2b2(float lo, float hi){
  bf16x2 t; t[0] = (__bf16)lo; t[1] = (__bf16)hi;
  return __builtin_bit_cast(unsigned, t);
}
__device__ __forceinline__ float b2f(unsigned short h){
  return __uint_as_float(((unsigned)h) << 16);
}
__device__ __forceinline__ f32x4 mfma16(short8 a, short8 b, f32x4 c){
  return __builtin_amdgcn_mfma_f32_16x16x32_bf16(a, b, c, 0, 0, 0);
}
union U8 { short8 v; unsigned u[4]; };
__device__ __forceinline__ void up8(uint4 q, float* x){
  x[0]=__uint_as_float(q.x<<16); x[1]=__uint_as_float(q.x&0xffff0000u);
  x[2]=__uint_as_float(q.y<<16); x[3]=__uint_as_float(q.y&0xffff0000u);
  x[4]=__uint_as_float(q.z<<16); x[5]=__uint_as_float(q.z&0xffff0000u);
  x[6]=__uint_as_float(q.w<<16); x[7]=__uint_as_float(q.w&0xffff0000u);
}
__device__ __forceinline__ float silu_f(float x){ return x/(1.f+__expf(-x)); }
__device__ __forceinline__ float sigm_f(float x){ return 1.f/(1.f+__expf(-x)); }

#define PACK8(a, s, x) \
  a.u[0]=f2b2((s)*(x)[0],(s)*(x)[1]); a.u[1]=f2b2((s)*(x)[2],(s)*(x)[3]); \
  a.u[2]=f2b2((s)*(x)[4],(s)*(x)[5]); a.u[3]=f2b2((s)*(x)[6],(s)*(x)[7]);

// ---------------- prep: repack weights into bf16 fragment order ----------------
// Constant-NT sections so the compiler magic-folds the div/mod.
#define PACKIDX(NTC, OFFC)                         \
  int q = idx - (OFFC);                            \
  int j = q & 7, lane = (q >> 3) & 63;             \
  int t = (q >> 9) % (NTC), c = q / ((NTC) << 9);  \
  int k = c*32 + ((lane >> 4) << 3) + j;           \
  int n = (t << 4) + (lane & 15);

__global__ void prep_weights(const float* __restrict__ ss_s, const float* __restrict__ vv_s,
                             const float* __restrict__ ss_g, const float* __restrict__ vv_g,
                             const float* __restrict__ sv,   const float* __restrict__ vs,
                             const float* __restrict__ w1,   const float* __restrict__ w2,
                             const float* __restrict__ w3,   unsigned short* __restrict__ wsb)
{
  int idx = blockIdx.x * 256 + threadIdx.x;
  if (idx >= N_TOTAL) return;
  const float A_SC  = 0.013975424859373686f;                       // 1/sqrt(S*S+V*V)
  const float A_VV  = (float)(0.013975424859373686 * 0.5773502691896258);
  const float A_VEC = 0.015625f;                                   // 1/sqrt(2*S*V)
  float v;
  if (idx < OFF_VV){
    PACKIDX(6, OFF_SS);
    v = A_SC * (n < 64 ? ss_s[k*64+n] : ss_g[k*32+(n-64)]);        // k=u*64+v
  } else if (idx < OFF_SV){
    PACKIDX(6, OFF_VV);
    v = A_VV * (n < 64 ? vv_s[k*64+n] : vv_g[k*32+(n-64)]);        // k=u*32+v
  } else if (idx < OFF_VS){
    PACKIDX(2, OFF_SV);
    v = A_VEC * sv[k*32+n];                                        // k=u*32+v
  } else if (idx < OFF_F1){
    PACKIDX(2, OFF_VS);
    v = A_VEC * vs[k*32+n];                                        // k=u*64+v
  } else if (idx < OFF_F2){
    PACKIDX(4, OFF_F1);
    v = w1[k*64+n];
  } else if (idx < OFF_F3){
    PACKIDX(4, OFF_F2);
    v = w2[k*64+n];
  } else {
    PACKIDX(6, OFF_F3);
    v = w3[k*96+n];
  }
  wsb[idx] = f2b(v);
}

// ---------------- main fused kernel ----------------
__global__ __launch_bounds__(256, 4)
void equiconv_main(const float* __restrict__ fea1,
                   const float* __restrict__ fea2,
                   const float* __restrict__ few,
                   const float* __restrict__ fb1,
                   const float* __restrict__ fb2,
                   const float* __restrict__ fb3,
                   const unsigned short* __restrict__ wsb,
                   float* __restrict__ out)
{
  __shared__ __align__(16) unsigned short ls_x1s[16][65];
  __shared__ __align__(16) unsigned short ls_x1v[16][97];
  __shared__ __align__(16) float          ls_x2s[16][64];
  __shared__ __align__(16) unsigned short ls_x2v[3][16][40];
  __shared__ __align__(16) unsigned short ls_h1[16][72];
  __shared__ __align__(16) unsigned short ls_h2[16][72];
  __shared__ __align__(16) float          red[12*16*20];   // 12 tile slots
  __shared__ __align__(16) float          wbuf[6*16*20];   // biased FC3 tiles

  const int ebase = blockIdx.x << 4;   // 1250 * 16 == 20000 exactly
  const int lane = threadIdx.x & 63;
  const int wv   = threadIdx.x >> 6;
  const int ln   = lane & 15;
  const int quad = lane >> 4;
  const int q8   = quad << 3;

  // ---- stage 16 edges of fea_in1 / fea_in2 into LDS ----
  for (int it = threadIdx.x; it < 640; it += 256){
    int row = it / 40, seg = it - row*40;
    int src = ebase + row;
    float4 v1 = *(const float4*)(fea1 + (size_t)src*160 + seg*4);
    float4 v2 = *(const float4*)(fea2 + (size_t)src*160 + seg*4);
    const float* p1 = (const float*)&v1;
    const float* p2 = (const float*)&v2;
    int c0 = seg*4;
    #pragma unroll
    for (int jj=0;jj<4;jj++){
      int col = c0 + jj;
      if (col < 64){
        ls_x1s[row][col] = f2b(p1[jj]);
        ls_x2s[row][col] = p2[jj];
      } else {
        int cv = col - 64;
        ls_x1v[row][cv] = f2b(p1[jj]);
        ls_x2v[cv%3][row][cv/3] = f2b(p2[jj]);
      }
    }
  }

  const f32x4 z4 = {0.f,0.f,0.f,0.f};

  // ---- FC1 (N-split: wave wv computes h1 tile wv; overlaps staging latency) ----
  {
    f32x4 accF = z4;
    const short8* B = (const short8*)(wsb + OFF_F1);
    const float* fwp = few + (size_t)(ebase + ln)*128;
    #pragma unroll
    for (int c=0;c<4;c++){
      float4 fa = *(const float4*)(fwp + c*32 + q8);
      float4 fbv = *(const float4*)(fwp + c*32 + q8 + 4);
      U8 a;
      a.u[0]=f2b2(fa.x,fa.y);   a.u[1]=f2b2(fa.z,fa.w);
      a.u[2]=f2b2(fbv.x,fbv.y); a.u[3]=f2b2(fbv.z,fbv.w);
      accF = mfma16(a.v, B[(c*4+wv)*64 + lane], accF);
    }
    float bb = fb1[wv*16+ln];
    __syncthreads();   // staging writes + (h1 writes below ordered before FC2's barrier)
    #pragma unroll
    for (int r=0;r<4;r++)
      ls_h1[(quad<<2)+r][wv*16+ln] = f2b(silu_f(accF[r] + bb));
  }
  __syncthreads();
  // ---- FC2: wave wv computes h2 tile wv ----
  {
    f32x4 accF = z4;
    const short8* B = (const short8*)(wsb + OFF_F2);
    #pragma unroll
    for (int c=0;c<2;c++){
      uint4 hq = *(const uint4*)&ls_h1[ln][c*32 + q8];
      U8 a; a.u[0]=hq.x; a.u[1]=hq.y; a.u[2]=hq.z; a.u[3]=hq.w;
      accF = mfma16(a.v, B[(c*4+wv)*64 + lane], accF);
    }
    float bb = fb2[wv*16+ln];
    __syncthreads();
    #pragma unroll
    for (int r=0;r<4;r++)
      ls_h2[(quad<<2)+r][wv*16+ln] = f2b(silu_f(accF[r] + bb));
  }
  __syncthreads();
  // ---- FC3: tiles {wv} + {wv+4 if wv<2}; write biased w-tiles to wbuf ----
  {
    const short8* B = (const short8*)(wsb + OFF_F3);
    #pragma unroll
    for (int pass=0; pass<2; pass++){
      int t = (pass == 0) ? wv : wv + 4;
      if (pass == 1 && wv >= 2) break;
      f32x4 accF = z4;
      #pragma unroll
      for (int c=0;c<2;c++){
        uint4 hq = *(const uint4*)&ls_h2[ln][c*32 + q8];
        U8 a; a.u[0]=hq.x; a.u[1]=hq.y; a.u[2]=hq.z; a.u[3]=hq.w;
        accF = mfma16(a.v, B[(c*6+t)*64 + lane], accF);
      }
      float bb = fb3[t*16+ln];
      f32x4 wt; 
      #pragma unroll
      for (int r=0;r<4;r++) wt[r] = accF[r] + bb;
      *(f32x4*)(wbuf + t*320 + ln*20 + (quad<<2)) = wt;
    }
  }
  // (wbuf consumption is after the reduce barriers — no barrier needed here)

  // ---- hoist per-lane x2 fragments (k = quad*8+j slices) ----
  float xe[8], xo[8], y0[8], y1[8], y2[8];
  {
    float4 a0 = *(const float4*)&ls_x2s[ln][q8];
    float4 a1 = *(const float4*)&ls_x2s[ln][q8+4];
    float4 b0 = *(const float4*)&ls_x2s[ln][32+q8];
    float4 b1 = *(const float4*)&ls_x2s[ln][36+q8];
    xe[0]=a0.x; xe[1]=a0.y; xe[2]=a0.z; xe[3]=a0.w;
    xe[4]=a1.x; xe[5]=a1.y; xe[6]=a1.z; xe[7]=a1.w;
    xo[0]=b0.x; xo[1]=b0.y; xo[2]=b0.z; xo[3]=b0.w;
    xo[4]=b1.x; xo[5]=b1.y; xo[6]=b1.z; xo[7]=b1.w;
    up8(*(const uint4*)&ls_x2v[0][ln][q8], y0);
    up8(*(const uint4*)&ls_x2v[1][ln][q8], y1);
    up8(*(const uint4*)&ls_x2v[2][ln][q8], y2);
  }

  // partial tiles: P[0..3]=sc, P[4,5]=g, P[6+3*tp+i]=vec comp i, tile tp
  f32x4 P[12] = {z4,z4,z4,z4,z4,z4,z4,z4,z4,z4,z4,z4};

  // ---- SS (u in wave's quarter of [0,64)) ----
  {
    const short8* B = (const short8*)(wsb + OFF_SS);
    const int u0 = wv << 4;
    #pragma unroll 2
    for (int u=u0; u<u0+16; u++){
      float s = b2f(ls_x1s[ln][u]);
      U8 a; PACK8(a, s, xe);
      const short8* bp = B + (u*12)*64 + lane;
      #pragma unroll
      for (int t=0;t<6;t++) P[t] = mfma16(a.v, bp[t*64], P[t]);
      PACK8(a, s, xo);
      bp += 6*64;
      #pragma unroll
      for (int t=0;t<6;t++) P[t] = mfma16(a.v, bp[t*64], P[t]);
    }
  }
  // ---- VV (u in quarter of [0,32)) ----
  {
    const short8* B = (const short8*)(wsb + OFF_VV);
    const int u0 = wv << 3;
    #pragma unroll 2
    for (int u=u0; u<u0+8; u++){
      float s0 = b2f(ls_x1v[ln][u*3+0]);
      float s1 = b2f(ls_x1v[ln][u*3+1]);
      float s2 = b2f(ls_x1v[ln][u*3+2]);
      float p[8];
      #pragma unroll
      for (int j=0;j<8;j++) p[j] = s0*y0[j] + s1*y1[j] + s2*y2[j];
      U8 a;
      a.u[0]=f2b2(p[0],p[1]); a.u[1]=f2b2(p[2],p[3]);
      a.u[2]=f2b2(p[4],p[5]); a.u[3]=f2b2(p[6],p[7]);
      const short8* bp = B + (u*6)*64 + lane;
      #pragma unroll
      for (int t=0;t<6;t++) P[t] = mfma16(a.v, bp[t*64], P[t]);
    }
  }
  // ---- SV (u in quarter of [0,64)) ----
  {
    const short8* B = (const short8*)(wsb + OFF_SV);
    const int u0 = wv << 4;
    #pragma unroll 2
    for (int u=u0; u<u0+16; u++){
      float s = b2f(ls_x1s[ln][u]);
      U8 a0, a1, a2;
      PACK8(a0, s, y0); PACK8(a1, s, y1); PACK8(a2, s, y2);
      const short8* bp = B + (u*2)*64 + lane;
      short8 bb0 = bp[0], bb1 = bp[64];
      P[6]=mfma16(a0.v,bb0,P[6]);  P[9] =mfma16(a0.v,bb1,P[9]);
      P[7]=mfma16(a1.v,bb0,P[7]);  P[10]=mfma16(a1.v,bb1,P[10]);
      P[8]=mfma16(a2.v,bb0,P[8]);  P[11]=mfma16(a2.v,bb1,P[11]);
    }
  }
  // ---- VS (u in quarter of [0,32)) ----
  {
    const short8* B = (const short8*)(wsb + OFF_VS);
    const int u0 = wv << 3;
    #pragma unroll 2
    for (int u=u0; u<u0+8; u++){
      float s0 = b2f(ls_x1v[ln][u*3+0]);
      float s1 = b2f(ls_x1v[ln][u*3+1]);
      float s2 = b2f(ls_x1v[ln][u*3+2]);
      const short8* bp = B + (u*4)*64 + lane;
      U8 a0, a1, a2;
      PACK8(a0, s0, xe); PACK8(a1, s1, xe); PACK8(a2, s2, xe);
      short8 bb0 = bp[0], bb1 = bp[64];
      P[6]=mfma16(a0.v,bb0,P[6]);  P[9] =mfma16(a0.v,bb1,P[9]);
      P[7]=mfma16(a1.v,bb0,P[7]);  P[10]=mfma16(a1.v,bb1,P[10]);
      P[8]=mfma16(a2.v,bb0,P[8]);  P[11]=mfma16(a2.v,bb1,P[11]);
      PACK8(a0, s0, xo); PACK8(a1, s1, xo); PACK8(a2, s2, xo);
      short8 bb2 = bp[128], bb3 = bp[192];
      P[6]=mfma16(a0.v,bb2,P[6]);  P[9] =mfma16(a0.v,bb3,P[9]);
      P[7]=mfma16(a1.v,bb2,P[7]);  P[10]=mfma16(a1.v,bb3,P[10]);
      P[8]=mfma16(a2.v,bb2,P[8]);  P[11]=mfma16(a2.v,bb3,P[11]);
    }
  }

  // ---- cross-wave K-reduction (pairwise exchange, 12-slot buffer) ----
  #define SLOT(s) ((f32x4*)(red + (s)*320 + ln*20 + (quad<<2)))
  const int pr6 = (wv >> 1) * 6;
  if (wv & 1){
    #pragma unroll
    for (int j=0;j<6;j++) *SLOT(pr6+j) = P[j];
  }
  __syncthreads();
  if (!(wv & 1)){
    #pragma unroll
    for (int j=0;j<6;j++) P[j] += *SLOT(pr6+j);
    #pragma unroll
    for (int j=0;j<6;j++) *SLOT(pr6+j) = P[6+j];
  }
  __syncthreads();
  if (wv & 1){
    #pragma unroll
    for (int j=0;j<6;j++) P[6+j] += *SLOT(pr6+j);
  }
  __syncthreads();
  if (wv == 2){
    #pragma unroll
    for (int j=0;j<6;j++) *SLOT(j) = P[j];
  }
  if (wv == 1){
    #pragma unroll
    for (int j=0;j<6;j++) *SLOT(6+j) = P[6+j];
  }
  __syncthreads();
  if (wv == 0){
    #pragma unroll
    for (int j=0;j<6;j++){ P[j] += *SLOT(j); *SLOT(j) = P[j]; }
  }
  if (wv == 3){
    #pragma unroll
    for (int j=0;j<6;j++){ P[6+j] += *SLOT(6+j); *SLOT(6+j) = P[6+j]; }
  }
  __syncthreads();

  // ---- epilogue: w0/w1 -> sc tiles, w2/w3 -> vec components ----
  #define WSLOT(s) ((const f32x4*)(wbuf + (s)*320 + ln*20 + (quad<<2)))
  if (wv < 2){
    #pragma unroll
    for (int tt=0; tt<2; tt++){
      int t = wv*2 + tt;
      f32x4 sc = *SLOT(t);
      f32x4 w  = *WSLOT(t);
      #pragma unroll
      for (int r=0;r<4;r++)
        out[(size_t)(ebase + (quad<<2) + r)*160 + t*16 + ln] = silu_f(sc[r]) * w[r];
    }
  } else {
    int tp = wv - 2;
    f32x4 g  = *SLOT(4+tp);
    f32x4 w  = *WSLOT(4+tp);
    f32x4 v0 = *SLOT(6+3*tp+0);
    f32x4 v1 = *SLOT(6+3*tp+1);
    f32x4 v2 = *SLOT(6+3*tp+2);
    #pragma unroll
    for (int r=0;r<4;r++){
      float f = sigm_f(g[r]) * w[r];
      float* op = out + (size_t)(ebase + (quad<<2) + r)*160 + 64 + (16*tp + ln)*3;
      op[0] = v0[r]*f; op[1] = v1[r]*f; op[2] = v2[r]*f;
    }
  }
}

extern "C" void kernel_launch(void* const* d_in, const int* in_sizes, int n_in,
                              void* d_out, int out_size, void* d_ws, size_t ws_size,
                              hipStream_t stream) {
  (void)in_sizes; (void)n_in; (void)out_size; (void)ws_size;
  const float* fea1 = (const float*)d_in[0];
  const float* fea2 = (const float*)d_in[1];
  const float* few  = (const float*)d_in[2];
  unsigned short* wsb = (unsigned short*)d_ws;

  prep_weights<<<(N_TOTAL + 255)/256, 256, 0, stream>>>(
      (const float*)d_in[3], (const float*)d_in[4],
      (const float*)d_in[5], (const float*)d_in[6],
      (const float*)d_in[7], (const float*)d_in[8],
      (const float*)d_in[9], (const float*)d_in[11], (const float*)d_in[13],
      wsb);

  equiconv_main<<<E_TOT/16, 256, 0, stream>>>(
      fea1, fea2, few,
      (const float*)d_in[10], (const float*)d_in[12], (const float*)d_in[14],
      (const unsigned short*)wsb, (float*)d_out);
}